// Round 15
// baseline (266.238 us; speedup 1.0000x reference)
//
#include <hip/hip_runtime.h>
#include <hip/hip_bf16.h>
#include <stdint.h>

#define DIN   4096
#define DOUT  4096
#define MTOT  8192

#define BK    64
#define NKT   (DIN / BK)   // 64 K-tiles

typedef int i32x4 __attribute__((ext_vector_type(4)));

__device__ __forceinline__ void glds16(const void* g, void* l) {
  __builtin_amdgcn_global_load_lds(
      (__attribute__((address_space(1))) void*)g,
      (__attribute__((address_space(3))) void*)l, 16, 0, 0);
}

// ---------------------------------------------------------------------------
// Kernel 1: per-row alpha (fp64 accumulate) + ternary quantize -> i8 {-1,0,1}
// ---------------------------------------------------------------------------
__global__ __launch_bounds__(256) void quant_w(const float* __restrict__ W,
                                               int8_t* __restrict__ QW) {
  const int row = blockIdx.x;
  const int t = threadIdx.x;
  const float* wr = W + (size_t)row * DIN;

  float4 v[4];
  double s = 0.0;
#pragma unroll
  for (int j = 0; j < 4; ++j) {
    v[j] = reinterpret_cast<const float4*>(wr)[j * 256 + t];
    s += (double)fabsf(v[j].x) + (double)fabsf(v[j].y) +
         (double)fabsf(v[j].z) + (double)fabsf(v[j].w);
  }
#pragma unroll
  for (int off = 32; off > 0; off >>= 1) s += __shfl_down(s, off, 64);

  __shared__ double ssum[4];
  __shared__ float salpha;
  if ((t & 63) == 0) ssum[t >> 6] = s;
  __syncthreads();
  if (t == 0) salpha = (float)((ssum[0] + ssum[1] + ssum[2] + ssum[3]) / (double)DIN);
  __syncthreads();
  const float alpha = salpha;

  int* qo = reinterpret_cast<int*>(QW + (size_t)row * DIN);
#pragma unroll
  for (int j = 0; j < 4; ++j) {
    int q0 = v[j].x > alpha ? 1 : (v[j].x < -alpha ? -1 : 0);
    int q1 = v[j].y > alpha ? 1 : (v[j].y < -alpha ? -1 : 0);
    int q2 = v[j].z > alpha ? 1 : (v[j].z < -alpha ? -1 : 0);
    int q3 = v[j].w > alpha ? 1 : (v[j].w < -alpha ? -1 : 0);
    qo[j * 256 + t] =
        (q0 & 0xff) | ((q1 & 0xff) << 8) | ((q2 & 0xff) << 16) | ((q3 & 0xff) << 24);
  }
}

// ---------------------------------------------------------------------------
// Kernel 2: x fp32 -> i8 with per-row scale. xq = rint(x * 127/rowmax),
// XS[row] = rowmax/127.
// ---------------------------------------------------------------------------
__global__ __launch_bounds__(256) void quant_x(const float* __restrict__ X,
                                               int8_t* __restrict__ XQ,
                                               float* __restrict__ XS) {
  const int row = blockIdx.x;
  const int t = threadIdx.x;
  const float* xr = X + (size_t)row * DIN;

  float4 v[4];
  float mx = 0.f;
#pragma unroll
  for (int j = 0; j < 4; ++j) {
    v[j] = reinterpret_cast<const float4*>(xr)[j * 256 + t];
    mx = fmaxf(mx, fmaxf(fmaxf(fabsf(v[j].x), fabsf(v[j].y)),
                         fmaxf(fabsf(v[j].z), fabsf(v[j].w))));
  }
#pragma unroll
  for (int off = 32; off > 0; off >>= 1) mx = fmaxf(mx, __shfl_down(mx, off, 64));

  __shared__ float smax[4];
  __shared__ float sinv, ssc;
  if ((t & 63) == 0) smax[t >> 6] = mx;
  __syncthreads();
  if (t == 0) {
    float rm = fmaxf(fmaxf(smax[0], smax[1]), fmaxf(smax[2], smax[3]));
    sinv = rm > 0.f ? 127.f / rm : 0.f;
    ssc  = rm > 0.f ? rm / 127.f : 0.f;
  }
  __syncthreads();
  const float inv = sinv;
  if (t == 0) XS[row] = ssc;

  int* qo = reinterpret_cast<int*>(XQ + (size_t)row * DIN);
#pragma unroll
  for (int j = 0; j < 4; ++j) {
    int q0 = (int)rintf(v[j].x * inv);
    int q1 = (int)rintf(v[j].y * inv);
    int q2 = (int)rintf(v[j].z * inv);
    int q3 = (int)rintf(v[j].w * inv);
    qo[j * 256 + t] =
        (q0 & 0xff) | ((q1 & 0xff) << 8) | ((q2 & 0xff) << 16) | ((q3 & 0xff) << 24);
  }
}

// ---------------------------------------------------------------------------
// Kernel 3: 256x256 i8 MFMA GEMM (mfma_i32_16x16x64_i8), round-15:
// r14 geometry (1024 thr, 16 waves 4x4, wave 64x64, 64 AGPR acc) with a
// DEEPER prefetch pipeline:
//   A: 4-buffered LDS (As[T&3]), issued at T.ph1 -> A(T+2)  (2 tiles flight)
//   B: 2-buffered LDS (Bs[T&1]), issued at T.ph2 -> B(T+2)  (1.5 tiles)
// LDS = 4*16 + 2*16 = 96 KB/block.
//
//   ph1: read a[4] (As[T&3]) + b[4] (Bs[T&1]); ISSUE A(T+2);
//        MMA ni={0,1} (8); LGKM0 (drains b[2..3]: overwrite anchor); BAR
//   ph2: ISSUE B(T+2); MMA ni={2,3} (8); vmcnt(2|0); BAR
//
// Overwrite audit:
//   A(T+2)->As[(T+2)&3]@T.ph1: that buffer's last LDS reads were tile T-2's
//     ph1 (a[4], consumed by T-2's MMAs, drained by T-2.ph1's LGKM0);
//     issuer crossed 4 barriers since.                                   OK
//   B(T+2)->Bs[T&1]@T.ph2: all Bs[T&1] reads at T.ph1, drained by ph1's
//     LGKM0 before ph1's BAR; issue after.                               OK
//   Tile T+1 reads gated by T.ph2's vmcnt+BAR.                           OK
// vmcnt ledger (per-wave stream: ...A(T+1)@(T-1).ph1, B(T+1)@(T-1).ph2,
//   A(T+2)@T.ph1, B(T+2)@T.ph2): at T.ph2 wait, exactly 2 loads trail
//   B(T+1) -> vmcnt(2) proves tile T+1 fully landed. vmcnt(0) T >= NKT-2.
// Swizzle: 16B chunk ^ ((row>>1)&3) (r9-r14: measured 0 conflicts).
// ---------------------------------------------------------------------------
__global__ __launch_bounds__(1024, 4) void gemm256_i8(
    const int8_t* __restrict__ XQ, const int8_t* __restrict__ QW,
    const float* __restrict__ XS, const float* __restrict__ scale,
    const float* __restrict__ bias, float* __restrict__ out) {
  __shared__ int8_t As[4][16384];  // 16 KB each buf (256 rows x 64 B)
  __shared__ int8_t Bs[2][16384];

  const int t = threadIdx.x;
  const int lane = t & 63;
  const int wid = t >> 6;
  const int wr = wid >> 2, wc = wid & 3;          // 4x4 wave grid
  const int m0 = blockIdx.x * 256;                // m fast-varying
  const int n0 = blockIdx.y * 256;

  const int8_t* ag = XQ + (size_t)m0 * DIN;
  const int8_t* bg = QW + (size_t)n0 * DIN;

  i32x4 acc[4][4] = {};            // [m-frag][n-frag], 64 AGPRs
  i32x4 a[4], b[4];

  const int r = lane & 15, kq = lane >> 4;        // frag row / 16B k-chunk
  const int srow = t >> 2;                        // staging row 0..255
  const int scol = ((t & 3) ^ ((srow >> 1) & 3)) * 16;  // inverse-swizzled src

// stage one full 256x64 A tile into As[ab_] (1 glds16/thread)
#define ISSUE_A(Tt_, ab_) do {                                                  \
    const int T_ = (Tt_);                                                       \
    if (T_ < NKT)                                                               \
      glds16(ag + (size_t)srow * DIN + T_ * 64 + scol, &As[ab_][0] + t * 16);   \
  } while (0)

#define ISSUE_B(Tt_, bb_) do {                                                  \
    const int T_ = (Tt_);                                                       \
    if (T_ < NKT)                                                               \
      glds16(bg + (size_t)srow * DIN + T_ * 64 + scol, &Bs[bb_][0] + t * 16);   \
  } while (0)

#define READA(ab_) do {                                                         \
    _Pragma("unroll")                                                           \
    for (int mi = 0; mi < 4; ++mi) {                                            \
      const int row_ = wr * 64 + mi * 16 + r;                                   \
      a[mi] = *reinterpret_cast<const i32x4*>(                                  \
          &As[ab_][row_ * 64 + (kq ^ ((row_ >> 1) & 3)) * 16]);                 \
    }                                                                           \
  } while (0)

#define READB(bb_) do {                                                         \
    _Pragma("unroll")                                                           \
    for (int ni = 0; ni < 4; ++ni) {                                            \
      const int row_ = wc * 64 + ni * 16 + r;                                   \
      b[ni] = *reinterpret_cast<const i32x4*>(                                  \
          &Bs[bb_][row_ * 64 + (kq ^ ((row_ >> 1) & 3)) * 16]);                 \
    }                                                                           \
  } while (0)

// 8 MFMA: all 4 m-frags x n-frags {nh*2, nh*2+1}
#define MMA8(nh_) do {                                                          \
    __builtin_amdgcn_s_setprio(1);                                              \
    _Pragma("unroll")                                                           \
    for (int mi = 0; mi < 4; ++mi) {                                            \
      _Pragma("unroll")                                                         \
      for (int ni = 0; ni < 2; ++ni) {                                          \
        acc[mi][(nh_) * 2 + ni] =                                               \
            __builtin_amdgcn_mfma_i32_16x16x64_i8(                              \
                a[mi], b[(nh_) * 2 + ni], acc[mi][(nh_) * 2 + ni], 0, 0, 0);    \
      }                                                                         \
    }                                                                           \
    __builtin_amdgcn_s_setprio(0);                                              \
  } while (0)

#define BAR() __builtin_amdgcn_s_barrier()
#define LGKM0() asm volatile("s_waitcnt lgkmcnt(0)" ::: "memory")

#define TILE(T_, ab_, bb_) do {                                                 \
    /* ph1 — A(T+2) overwrite legal: As[(T+2)&3] last read at tile T-2 */       \
    READA(ab_);                                                                 \
    READB(bb_);                                                                 \
    ISSUE_A((T_) + 2, ((T_) + 2) & 3);                                          \
    MMA8(0);                                                                    \
    LGKM0();  /* drain b[2..3] (consumed ph2) before BAR: overwrite anchor */   \
    BAR();                                                                      \
    /* ph2 — B(T+2) overwrite legal: Bs[bb_] reads drained at ph1 anchor */     \
    ISSUE_B((T_) + 2, bb_);                                                     \
    MMA8(1);                                                                    \
    if ((T_) < NKT - 2)                                                         \
      asm volatile("s_waitcnt vmcnt(2)" ::: "memory");                          \
    else                                                                        \
      asm volatile("s_waitcnt vmcnt(0)" ::: "memory");                          \
    BAR();                                                                      \
  } while (0)

  // prologue: A(0), B(0), A(1), B(1) — 4 loads, ordered to match the
  // steady-state ledger. vmcnt(2) => A(0), B(0) landed.
  ISSUE_A(0, 0); ISSUE_B(0, 0); ISSUE_A(1, 1); ISSUE_B(1, 1);
  asm volatile("s_waitcnt vmcnt(2)" ::: "memory");
  __builtin_amdgcn_s_barrier();

  for (int T = 0; T < NKT; T += 4) {
    TILE(T,     (T) & 3,     0);
    TILE(T + 1, (T + 1) & 3, 1);
    TILE(T + 2, (T + 2) & 3, 0);
    TILE(T + 3, (T + 3) & 3, 1);
  }

  // epilogue: C/D lane map col=lane&15, row=(lane>>4)*4+e (dtype-independent)
  const int q4 = lane >> 4;
#pragma unroll
  for (int ni = 0; ni < 4; ++ni) {
    const int col = n0 + wc * 64 + ni * 16 + r;
    const float sc = scale[col];
    const float bs = bias[col];
#pragma unroll
    for (int mi = 0; mi < 4; ++mi) {
      const int row = m0 + wr * 64 + mi * 16 + q4 * 4;
#pragma unroll
      for (int e = 0; e < 4; ++e) {
        const float xs = XS[row + e];
        out[(size_t)(row + e) * DOUT + col] =
            (float)acc[mi][ni][e] * (xs * sc) + bs;
      }
    }
  }
#undef ISSUE_A
#undef ISSUE_B
#undef READA
#undef READB
#undef MMA8
#undef BAR
#undef LGKM0
#undef TILE
}

extern "C" void kernel_launch(void* const* d_in, const int* in_sizes, int n_in,
                              void* d_out, int out_size, void* d_ws, size_t ws_size,
                              hipStream_t stream) {
  const float* X     = (const float*)d_in[0];
  const float* W     = (const float*)d_in[1];
  const float* scale = (const float*)d_in[2];
  const float* bias  = (const float*)d_in[3];
  float* out = (float*)d_out;

  // ws layout: QW i8 16 MB | XQ i8 32 MB | XS fp32 32 KB
  int8_t* QW = (int8_t*)d_ws;
  int8_t* XQ = (int8_t*)d_ws + (size_t)DOUT * DIN;
  float*  XS = (float*)((int8_t*)d_ws + (size_t)DOUT * DIN + (size_t)MTOT * DIN);

  quant_w<<<DOUT, 256, 0, stream>>>(W, QW);
  quant_x<<<MTOT, 256, 0, stream>>>(X, XQ, XS);
  dim3 grid(MTOT / 256, DOUT / 256);
  gemm256_i8<<<grid, 1024, 0, stream>>>(XQ, QW, XS, scale, bias, out);
}

// Round 16
// 197.742 us; speedup vs baseline: 1.3464x; 1.3464x over previous
//
#include <hip/hip_runtime.h>
#include <hip/hip_bf16.h>
#include <stdint.h>

#define DIN   4096
#define DOUT  4096
#define MTOT  8192

#define BK    64
#define NKT   (DIN / BK)   // 64 K-tiles

typedef int i32x4 __attribute__((ext_vector_type(4)));

__device__ __forceinline__ void glds16(const void* g, void* l) {
  __builtin_amdgcn_global_load_lds(
      (__attribute__((address_space(1))) void*)g,
      (__attribute__((address_space(3))) void*)l, 16, 0, 0);
}

// ---------------------------------------------------------------------------
// Kernel 1: per-row alpha (fp64 accumulate) + ternary quantize -> i8 {-1,0,1}
// ---------------------------------------------------------------------------
__global__ __launch_bounds__(256) void quant_w(const float* __restrict__ W,
                                               int8_t* __restrict__ QW) {
  const int row = blockIdx.x;
  const int t = threadIdx.x;
  const float* wr = W + (size_t)row * DIN;

  float4 v[4];
  double s = 0.0;
#pragma unroll
  for (int j = 0; j < 4; ++j) {
    v[j] = reinterpret_cast<const float4*>(wr)[j * 256 + t];
    s += (double)fabsf(v[j].x) + (double)fabsf(v[j].y) +
         (double)fabsf(v[j].z) + (double)fabsf(v[j].w);
  }
#pragma unroll
  for (int off = 32; off > 0; off >>= 1) s += __shfl_down(s, off, 64);

  __shared__ double ssum[4];
  __shared__ float salpha;
  if ((t & 63) == 0) ssum[t >> 6] = s;
  __syncthreads();
  if (t == 0) salpha = (float)((ssum[0] + ssum[1] + ssum[2] + ssum[3]) / (double)DIN);
  __syncthreads();
  const float alpha = salpha;

  int* qo = reinterpret_cast<int*>(QW + (size_t)row * DIN);
#pragma unroll
  for (int j = 0; j < 4; ++j) {
    int q0 = v[j].x > alpha ? 1 : (v[j].x < -alpha ? -1 : 0);
    int q1 = v[j].y > alpha ? 1 : (v[j].y < -alpha ? -1 : 0);
    int q2 = v[j].z > alpha ? 1 : (v[j].z < -alpha ? -1 : 0);
    int q3 = v[j].w > alpha ? 1 : (v[j].w < -alpha ? -1 : 0);
    qo[j * 256 + t] =
        (q0 & 0xff) | ((q1 & 0xff) << 8) | ((q2 & 0xff) << 16) | ((q3 & 0xff) << 24);
  }
}

// ---------------------------------------------------------------------------
// Kernel 2: x fp32 -> i8 with per-row scale. xq = rint(x * 127/rowmax),
// XS[row] = rowmax/127.
// ---------------------------------------------------------------------------
__global__ __launch_bounds__(256) void quant_x(const float* __restrict__ X,
                                               int8_t* __restrict__ XQ,
                                               float* __restrict__ XS) {
  const int row = blockIdx.x;
  const int t = threadIdx.x;
  const float* xr = X + (size_t)row * DIN;

  float4 v[4];
  float mx = 0.f;
#pragma unroll
  for (int j = 0; j < 4; ++j) {
    v[j] = reinterpret_cast<const float4*>(xr)[j * 256 + t];
    mx = fmaxf(mx, fmaxf(fmaxf(fabsf(v[j].x), fabsf(v[j].y)),
                         fmaxf(fabsf(v[j].z), fabsf(v[j].w))));
  }
#pragma unroll
  for (int off = 32; off > 0; off >>= 1) mx = fmaxf(mx, __shfl_down(mx, off, 64));

  __shared__ float smax[4];
  __shared__ float sinv, ssc;
  if ((t & 63) == 0) smax[t >> 6] = mx;
  __syncthreads();
  if (t == 0) {
    float rm = fmaxf(fmaxf(smax[0], smax[1]), fmaxf(smax[2], smax[3]));
    sinv = rm > 0.f ? 127.f / rm : 0.f;
    ssc  = rm > 0.f ? rm / 127.f : 0.f;
  }
  __syncthreads();
  const float inv = sinv;
  if (t == 0) XS[row] = ssc;

  int* qo = reinterpret_cast<int*>(XQ + (size_t)row * DIN);
#pragma unroll
  for (int j = 0; j < 4; ++j) {
    int q0 = (int)rintf(v[j].x * inv);
    int q1 = (int)rintf(v[j].y * inv);
    int q2 = (int)rintf(v[j].z * inv);
    int q3 = (int)rintf(v[j].w * inv);
    qo[j * 256 + t] =
        (q0 & 0xff) | ((q1 & 0xff) << 8) | ((q2 & 0xff) << 16) | ((q3 & 0xff) << 24);
  }
}

// ---------------------------------------------------------------------------
// Kernel 3: 256x256 i8 MFMA GEMM (mfma_i32_16x16x64_i8), round-16 =
// r14 (best measured: 152 us GEMM) with s_setprio removed (m190: null-to-
// negative on lockstep GEMM) and float4 XS epilogue loads.
//
// Geometry: 1024 thr = 16 waves (4Mx4N), wave owns 64x64
// (acc = 16 x i32x4 = 64 AGPR, ~128 regs/wave -> 16 waves/CU).
// LDS: A/B [256 rows][64 B] i8 dbuf = 64 KB/block. One glds16/thread stages
// a whole 256x64 operand tile.
//
// 2 windows/tile (r11-proven invariant):
//   ph1: read a[4]+b[4] (8 ds_read); ISSUE A(T+1); MMA ni={0,1} (8); BAR
//   ph2: ISSUE B(T+2); MMA ni={2,3} (8); vmcnt(1|0); BAR
//
// Overwrite audit:
//   A(T+1)->As[buf^1]@ph1: As[buf^1] LDS reads were (T-1).ph1, consumed by
//     (T-1).ph1's MMA before its BAR; issuer crossed (T-1).ph2 BAR.     OK
//   B(T+2)->Bs[buf]@ph2: all Bs[buf] reads at T.ph1, consumed by T.ph1's
//     MMA before T.ph1's BAR; issue after.                              OK
//   Tile T+1 reads gated by T.ph2's vmcnt+BAR.                          OK
// vmcnt ledger (per-wave stream: ...B(T+1)@(T-1).ph2 < A(T+1)@T.ph1 <
//   B(T+2)@T.ph2, 1 instr each): at T.ph2 wait, vmcnt(1) => everything
//   through A(T+1) landed. vmcnt(0) for T >= NKT-2.
// Swizzle: 16B chunk ^ ((row>>1)&3) (r9-r14: measured 0 conflicts).
// ---------------------------------------------------------------------------
__global__ __launch_bounds__(1024, 4) void gemm256_i8(
    const int8_t* __restrict__ XQ, const int8_t* __restrict__ QW,
    const float* __restrict__ XS, const float* __restrict__ scale,
    const float* __restrict__ bias, float* __restrict__ out) {
  __shared__ int8_t As[2][16384];  // 16 KB each buf (256 rows x 64 B)
  __shared__ int8_t Bs[2][16384];

  const int t = threadIdx.x;
  const int lane = t & 63;
  const int wid = t >> 6;
  const int wr = wid >> 2, wc = wid & 3;          // 4x4 wave grid
  const int m0 = blockIdx.x * 256;                // m fast-varying
  const int n0 = blockIdx.y * 256;

  const int8_t* ag = XQ + (size_t)m0 * DIN;
  const int8_t* bg = QW + (size_t)n0 * DIN;

  i32x4 acc[4][4] = {};            // [m-frag][n-frag], 64 AGPRs
  i32x4 a[4], b[4];

  const int r = lane & 15, kq = lane >> 4;        // frag row / 16B k-chunk
  const int srow = t >> 2;                        // staging row 0..255
  const int scol = ((t & 3) ^ ((srow >> 1) & 3)) * 16;  // inverse-swizzled src

// stage one full 256x64 operand tile (1 glds16/thread)
#define ISSUE_T(Tt_, isb_) do {                                                 \
    const int T_ = (Tt_);                                                       \
    if (T_ < NKT) {                                                             \
      const int bf_ = T_ & 1;                                                   \
      const int8_t* gb_ = (isb_) ? bg : ag;                                     \
      int8_t* lb_ = (isb_) ? &Bs[bf_][0] : &As[bf_][0];                         \
      glds16(gb_ + (size_t)srow * DIN + T_ * 64 + scol, lb_ + t * 16);          \
    }                                                                           \
  } while (0)

#define READA(buf_) do {                                                        \
    _Pragma("unroll")                                                           \
    for (int mi = 0; mi < 4; ++mi) {                                            \
      const int row_ = wr * 64 + mi * 16 + r;                                   \
      a[mi] = *reinterpret_cast<const i32x4*>(                                  \
          &As[buf_][row_ * 64 + (kq ^ ((row_ >> 1) & 3)) * 16]);                \
    }                                                                           \
  } while (0)

#define READB(buf_) do {                                                        \
    _Pragma("unroll")                                                           \
    for (int ni = 0; ni < 4; ++ni) {                                            \
      const int row_ = wc * 64 + ni * 16 + r;                                   \
      b[ni] = *reinterpret_cast<const i32x4*>(                                  \
          &Bs[buf_][row_ * 64 + (kq ^ ((row_ >> 1) & 3)) * 16]);                \
    }                                                                           \
  } while (0)

// 8 MFMA: all 4 m-frags x n-frags {nh*2, nh*2+1}  (no setprio: lockstep
// waves, m190 evidence)
#define MMA8(nh_) do {                                                          \
    _Pragma("unroll")                                                           \
    for (int mi = 0; mi < 4; ++mi) {                                            \
      _Pragma("unroll")                                                         \
      for (int ni = 0; ni < 2; ++ni) {                                          \
        acc[mi][(nh_) * 2 + ni] =                                               \
            __builtin_amdgcn_mfma_i32_16x16x64_i8(                              \
                a[mi], b[(nh_) * 2 + ni], acc[mi][(nh_) * 2 + ni], 0, 0, 0);    \
      }                                                                         \
    }                                                                           \
  } while (0)

#define BAR() __builtin_amdgcn_s_barrier()

#define TILE(T_, buf_) do {                                                     \
    /* ph1 — A(T+1) overwrite legal: As[buf^1] consumed at (T-1).ph1 */         \
    READA(buf_);                                                                \
    READB(buf_);                                                                \
    ISSUE_T((T_) + 1, 0);                                                       \
    MMA8(0);                                                                    \
    BAR();                                                                      \
    /* ph2 — B(T+2) overwrite legal: Bs[buf] consumed at T.ph1 */               \
    ISSUE_T((T_) + 2, 1);                                                       \
    MMA8(1);                                                                    \
    if ((T_) < NKT - 2)                                                         \
      asm volatile("s_waitcnt vmcnt(1)" ::: "memory");                          \
    else                                                                        \
      asm volatile("s_waitcnt vmcnt(0)" ::: "memory");                          \
    BAR();                                                                      \
  } while (0)

  // prologue: A(0), B(0), B(1) — 3 glds/thread, stream order matches steady
  // state. vmcnt(1) => A(0), B(0) landed (B(1) may remain in flight).
  ISSUE_T(0, 0); ISSUE_T(0, 1); ISSUE_T(1, 1);
  asm volatile("s_waitcnt vmcnt(1)" ::: "memory");
  __builtin_amdgcn_s_barrier();

  for (int T = 0; T < NKT; T += 2) {
    TILE(T, 0);
    TILE(T + 1, 1);
  }

  // epilogue: C/D lane map col=lane&15, row=(lane>>4)*4+e (dtype-independent)
  const int q4 = lane >> 4;
#pragma unroll
  for (int ni = 0; ni < 4; ++ni) {
    const int col = n0 + wc * 64 + ni * 16 + r;
    const float sc = scale[col];
    const float bs = bias[col];
#pragma unroll
    for (int mi = 0; mi < 4; ++mi) {
      const int row = m0 + wr * 64 + mi * 16 + q4 * 4;
      const float4 xs4 = *reinterpret_cast<const float4*>(&XS[row]);
      out[(size_t)(row + 0) * DOUT + col] = (float)acc[mi][ni][0] * (xs4.x * sc) + bs;
      out[(size_t)(row + 1) * DOUT + col] = (float)acc[mi][ni][1] * (xs4.y * sc) + bs;
      out[(size_t)(row + 2) * DOUT + col] = (float)acc[mi][ni][2] * (xs4.z * sc) + bs;
      out[(size_t)(row + 3) * DOUT + col] = (float)acc[mi][ni][3] * (xs4.w * sc) + bs;
    }
  }
#undef ISSUE_T
#undef READA
#undef READB
#undef MMA8
#undef BAR
#undef TILE
}

extern "C" void kernel_launch(void* const* d_in, const int* in_sizes, int n_in,
                              void* d_out, int out_size, void* d_ws, size_t ws_size,
                              hipStream_t stream) {
  const float* X     = (const float*)d_in[0];
  const float* W     = (const float*)d_in[1];
  const float* scale = (const float*)d_in[2];
  const float* bias  = (const float*)d_in[3];
  float* out = (float*)d_out;

  // ws layout: QW i8 16 MB | XQ i8 32 MB | XS fp32 32 KB
  int8_t* QW = (int8_t*)d_ws;
  int8_t* XQ = (int8_t*)d_ws + (size_t)DOUT * DIN;
  float*  XS = (float*)((int8_t*)d_ws + (size_t)DOUT * DIN + (size_t)MTOT * DIN);

  quant_w<<<DOUT, 256, 0, stream>>>(W, QW);
  quant_x<<<MTOT, 256, 0, stream>>>(X, XQ, XS);
  dim3 grid(MTOT / 256, DOUT / 256);
  gemm256_i8<<<grid, 1024, 0, stream>>>(XQ, QW, XS, scale, bias, out);
}

// Round 17
// 194.237 us; speedup vs baseline: 1.3707x; 1.0180x over previous
//
#include <hip/hip_runtime.h>
#include <hip/hip_bf16.h>
#include <stdint.h>

#define DIN   4096
#define DOUT  4096
#define MTOT  8192

#define BK    64
#define NKT   (DIN / BK)   // 64 K-tiles

typedef int i32x4 __attribute__((ext_vector_type(4)));

__device__ __forceinline__ void glds16(const void* g, void* l) {
  __builtin_amdgcn_global_load_lds(
      (__attribute__((address_space(1))) void*)g,
      (__attribute__((address_space(3))) void*)l, 16, 0, 0);
}

// ---------------------------------------------------------------------------
// Fused prep kernel (one launch, 12288 blocks):
//   blocks [0, DOUT):        per-row alpha (fp64) + ternary quantize W -> i8
//   blocks [DOUT, DOUT+MTOT): per-row max + quantize X -> i8, XS[row]
// Both paths are HBM-bound; fusing removes the serialization bubble between
// the two launches (independent work, full-device occupancy throughout).
// ---------------------------------------------------------------------------
__global__ __launch_bounds__(256) void quant_fused(
    const float* __restrict__ W, int8_t* __restrict__ QW,
    const float* __restrict__ X, int8_t* __restrict__ XQ,
    float* __restrict__ XS) {
  const int t = threadIdx.x;

  if (blockIdx.x < DOUT) {
    // ---- W path: ternary quantize with fp64-accumulated alpha ----
    const int row = blockIdx.x;
    const float* wr = W + (size_t)row * DIN;

    float4 v[4];
    double s = 0.0;
#pragma unroll
    for (int j = 0; j < 4; ++j) {
      v[j] = reinterpret_cast<const float4*>(wr)[j * 256 + t];
      s += (double)fabsf(v[j].x) + (double)fabsf(v[j].y) +
           (double)fabsf(v[j].z) + (double)fabsf(v[j].w);
    }
#pragma unroll
    for (int off = 32; off > 0; off >>= 1) s += __shfl_down(s, off, 64);

    __shared__ double ssum[4];
    __shared__ float salpha;
    if ((t & 63) == 0) ssum[t >> 6] = s;
    __syncthreads();
    if (t == 0)
      salpha = (float)((ssum[0] + ssum[1] + ssum[2] + ssum[3]) / (double)DIN);
    __syncthreads();
    const float alpha = salpha;

    int* qo = reinterpret_cast<int*>(QW + (size_t)row * DIN);
#pragma unroll
    for (int j = 0; j < 4; ++j) {
      int q0 = v[j].x > alpha ? 1 : (v[j].x < -alpha ? -1 : 0);
      int q1 = v[j].y > alpha ? 1 : (v[j].y < -alpha ? -1 : 0);
      int q2 = v[j].z > alpha ? 1 : (v[j].z < -alpha ? -1 : 0);
      int q3 = v[j].w > alpha ? 1 : (v[j].w < -alpha ? -1 : 0);
      qo[j * 256 + t] =
          (q0 & 0xff) | ((q1 & 0xff) << 8) | ((q2 & 0xff) << 16) | ((q3 & 0xff) << 24);
    }
  } else {
    // ---- X path: per-row absmax scale quantize ----
    const int row = blockIdx.x - DOUT;
    const float* xr = X + (size_t)row * DIN;

    float4 v[4];
    float mx = 0.f;
#pragma unroll
    for (int j = 0; j < 4; ++j) {
      v[j] = reinterpret_cast<const float4*>(xr)[j * 256 + t];
      mx = fmaxf(mx, fmaxf(fmaxf(fabsf(v[j].x), fabsf(v[j].y)),
                           fmaxf(fabsf(v[j].z), fabsf(v[j].w))));
    }
#pragma unroll
    for (int off = 32; off > 0; off >>= 1) mx = fmaxf(mx, __shfl_down(mx, off, 64));

    __shared__ float smax[4];
    __shared__ float sinv, ssc;
    if ((t & 63) == 0) smax[t >> 6] = mx;
    __syncthreads();
    if (t == 0) {
      float rm = fmaxf(fmaxf(smax[0], smax[1]), fmaxf(smax[2], smax[3]));
      sinv = rm > 0.f ? 127.f / rm : 0.f;
      ssc  = rm > 0.f ? rm / 127.f : 0.f;
    }
    __syncthreads();
    const float inv = sinv;
    if (t == 0) XS[row] = ssc;

    int* qo = reinterpret_cast<int*>(XQ + (size_t)row * DIN);
#pragma unroll
    for (int j = 0; j < 4; ++j) {
      int q0 = (int)rintf(v[j].x * inv);
      int q1 = (int)rintf(v[j].y * inv);
      int q2 = (int)rintf(v[j].z * inv);
      int q3 = (int)rintf(v[j].w * inv);
      qo[j * 256 + t] =
          (q0 & 0xff) | ((q1 & 0xff) << 8) | ((q2 & 0xff) << 16) | ((q3 & 0xff) << 24);
    }
  }
}

// ---------------------------------------------------------------------------
// GEMM kernel: byte-identical to round-16 (best measured: 151.7 us).
// 256x256 i8 MFMA GEMM (mfma_i32_16x16x64_i8).
// Geometry: 1024 thr = 16 waves (4Mx4N), wave owns 64x64
// (acc = 16 x i32x4 = 64 AGPR, ~128 regs/wave -> 16 waves/CU).
// LDS: A/B [256 rows][64 B] i8 dbuf = 64 KB/block. One glds16/thread stages
// a whole 256x64 operand tile.
//
// 2 windows/tile (r11-proven invariant):
//   ph1: read a[4]+b[4] (8 ds_read); ISSUE A(T+1); MMA ni={0,1} (8); BAR
//   ph2: ISSUE B(T+2); MMA ni={2,3} (8); vmcnt(1|0); BAR
//
// Overwrite audit:
//   A(T+1)->As[buf^1]@ph1: As[buf^1] LDS reads were (T-1).ph1, consumed by
//     (T-1).ph1's MMA before its BAR; issuer crossed (T-1).ph2 BAR.     OK
//   B(T+2)->Bs[buf]@ph2: all Bs[buf] reads at T.ph1, consumed by T.ph1's
//     MMA before T.ph1's BAR; issue after.                              OK
//   Tile T+1 reads gated by T.ph2's vmcnt+BAR.                          OK
// vmcnt ledger (per-wave stream: ...B(T+1)@(T-1).ph2 < A(T+1)@T.ph1 <
//   B(T+2)@T.ph2, 1 instr each): at T.ph2 wait, vmcnt(1) => everything
//   through A(T+1) landed. vmcnt(0) for T >= NKT-2.
// Swizzle: 16B chunk ^ ((row>>1)&3) (r9-r16: measured 0 conflicts).
// ---------------------------------------------------------------------------
__global__ __launch_bounds__(1024, 4) void gemm256_i8(
    const int8_t* __restrict__ XQ, const int8_t* __restrict__ QW,
    const float* __restrict__ XS, const float* __restrict__ scale,
    const float* __restrict__ bias, float* __restrict__ out) {
  __shared__ int8_t As[2][16384];  // 16 KB each buf (256 rows x 64 B)
  __shared__ int8_t Bs[2][16384];

  const int t = threadIdx.x;
  const int lane = t & 63;
  const int wid = t >> 6;
  const int wr = wid >> 2, wc = wid & 3;          // 4x4 wave grid
  const int m0 = blockIdx.x * 256;                // m fast-varying
  const int n0 = blockIdx.y * 256;

  const int8_t* ag = XQ + (size_t)m0 * DIN;
  const int8_t* bg = QW + (size_t)n0 * DIN;

  i32x4 acc[4][4] = {};            // [m-frag][n-frag], 64 AGPRs
  i32x4 a[4], b[4];

  const int r = lane & 15, kq = lane >> 4;        // frag row / 16B k-chunk
  const int srow = t >> 2;                        // staging row 0..255
  const int scol = ((t & 3) ^ ((srow >> 1) & 3)) * 16;  // inverse-swizzled src

// stage one full 256x64 operand tile (1 glds16/thread)
#define ISSUE_T(Tt_, isb_) do {                                                 \
    const int T_ = (Tt_);                                                       \
    if (T_ < NKT) {                                                             \
      const int bf_ = T_ & 1;                                                   \
      const int8_t* gb_ = (isb_) ? bg : ag;                                     \
      int8_t* lb_ = (isb_) ? &Bs[bf_][0] : &As[bf_][0];                         \
      glds16(gb_ + (size_t)srow * DIN + T_ * 64 + scol, lb_ + t * 16);          \
    }                                                                           \
  } while (0)

#define READA(buf_) do {                                                        \
    _Pragma("unroll")                                                           \
    for (int mi = 0; mi < 4; ++mi) {                                            \
      const int row_ = wr * 64 + mi * 16 + r;                                   \
      a[mi] = *reinterpret_cast<const i32x4*>(                                  \
          &As[buf_][row_ * 64 + (kq ^ ((row_ >> 1) & 3)) * 16]);                \
    }                                                                           \
  } while (0)

#define READB(buf_) do {                                                        \
    _Pragma("unroll")                                                           \
    for (int ni = 0; ni < 4; ++ni) {                                            \
      const int row_ = wc * 64 + ni * 16 + r;                                   \
      b[ni] = *reinterpret_cast<const i32x4*>(                                  \
          &Bs[buf_][row_ * 64 + (kq ^ ((row_ >> 1) & 3)) * 16]);                \
    }                                                                           \
  } while (0)

// 8 MFMA: all 4 m-frags x n-frags {nh*2, nh*2+1}
#define MMA8(nh_) do {                                                          \
    _Pragma("unroll")                                                           \
    for (int mi = 0; mi < 4; ++mi) {                                            \
      _Pragma("unroll")                                                         \
      for (int ni = 0; ni < 2; ++ni) {                                          \
        acc[mi][(nh_) * 2 + ni] =                                               \
            __builtin_amdgcn_mfma_i32_16x16x64_i8(                              \
                a[mi], b[(nh_) * 2 + ni], acc[mi][(nh_) * 2 + ni], 0, 0, 0);    \
      }                                                                         \
    }                                                                           \
  } while (0)

#define BAR() __builtin_amdgcn_s_barrier()

#define TILE(T_, buf_) do {                                                     \
    /* ph1 — A(T+1) overwrite legal: As[buf^1] consumed at (T-1).ph1 */         \
    READA(buf_);                                                                \
    READB(buf_);                                                                \
    ISSUE_T((T_) + 1, 0);                                                       \
    MMA8(0);                                                                    \
    BAR();                                                                      \
    /* ph2 — B(T+2) overwrite legal: Bs[buf] consumed at T.ph1 */               \
    ISSUE_T((T_) + 2, 1);                                                       \
    MMA8(1);                                                                    \
    if ((T_) < NKT - 2)                                                         \
      asm volatile("s_waitcnt vmcnt(1)" ::: "memory");                          \
    else                                                                        \
      asm volatile("s_waitcnt vmcnt(0)" ::: "memory");                          \
    BAR();                                                                      \
  } while (0)

  // prologue: A(0), B(0), B(1) — 3 glds/thread, stream order matches steady
  // state. vmcnt(1) => A(0), B(0) landed (B(1) may remain in flight).
  ISSUE_T(0, 0); ISSUE_T(0, 1); ISSUE_T(1, 1);
  asm volatile("s_waitcnt vmcnt(1)" ::: "memory");
  __builtin_amdgcn_s_barrier();

  for (int T = 0; T < NKT; T += 2) {
    TILE(T, 0);
    TILE(T + 1, 1);
  }

  // epilogue: C/D lane map col=lane&15, row=(lane>>4)*4+e (dtype-independent)
  const int q4 = lane >> 4;
#pragma unroll
  for (int ni = 0; ni < 4; ++ni) {
    const int col = n0 + wc * 64 + ni * 16 + r;
    const float sc = scale[col];
    const float bs = bias[col];
#pragma unroll
    for (int mi = 0; mi < 4; ++mi) {
      const int row = m0 + wr * 64 + mi * 16 + q4 * 4;
      const float4 xs4 = *reinterpret_cast<const float4*>(&XS[row]);
      out[(size_t)(row + 0) * DOUT + col] = (float)acc[mi][ni][0] * (xs4.x * sc) + bs;
      out[(size_t)(row + 1) * DOUT + col] = (float)acc[mi][ni][1] * (xs4.y * sc) + bs;
      out[(size_t)(row + 2) * DOUT + col] = (float)acc[mi][ni][2] * (xs4.z * sc) + bs;
      out[(size_t)(row + 3) * DOUT + col] = (float)acc[mi][ni][3] * (xs4.w * sc) + bs;
    }
  }
#undef ISSUE_T
#undef READA
#undef READB
#undef MMA8
#undef BAR
#undef TILE
}

extern "C" void kernel_launch(void* const* d_in, const int* in_sizes, int n_in,
                              void* d_out, int out_size, void* d_ws, size_t ws_size,
                              hipStream_t stream) {
  const float* X     = (const float*)d_in[0];
  const float* W     = (const float*)d_in[1];
  const float* scale = (const float*)d_in[2];
  const float* bias  = (const float*)d_in[3];
  float* out = (float*)d_out;

  // ws layout: QW i8 16 MB | XQ i8 32 MB | XS fp32 32 KB
  int8_t* QW = (int8_t*)d_ws;
  int8_t* XQ = (int8_t*)d_ws + (size_t)DOUT * DIN;
  float*  XS = (float*)((int8_t*)d_ws + (size_t)DOUT * DIN + (size_t)MTOT * DIN);

  quant_fused<<<DOUT + MTOT, 256, 0, stream>>>(W, QW, X, XQ, XS);
  dim3 grid(MTOT / 256, DOUT / 256);
  gemm256_i8<<<grid, 1024, 0, stream>>>(XQ, QW, XS, scale, bias, out);
}